// Round 8
// baseline (258.005 us; speedup 1.0000x reference)
//
#include <hip/hip_runtime.h>

namespace {
constexpr int NB = 256, NN = 1024, DIN = 64, HID = 256, DOUT = 128;
constexpr int MT = 64;               // rows per tile
constexpr int NH2 = 512;             // rows per half-pipeline

typedef __attribute__((ext_vector_type(8))) short bf16x8;
typedef __attribute__((ext_vector_type(4))) float f32x4;

__device__ inline unsigned short f2bf(float f) {   // RNE float->bf16
    union { float f; unsigned u; } v; v.f = f;
    unsigned r = v.u + 0x7FFF + ((v.u >> 16) & 1);
    return (unsigned short)(r >> 16);
}

// fp32 GEMV segment, 1024 threads: c=t&63 (4 cols of 64 float4), s=t>>6 (16 k-segs of 16)
__device__ inline float4 dotseg16(const float* __restrict__ buf, const float* __restrict__ W,
                                  int c, int s) {
    const float4* W4 = (const float4*)W;           // rows of 64 float4 (N=256)
    float4 acc = make_float4(0.f, 0.f, 0.f, 0.f);
#pragma unroll 8
    for (int i = 0; i < 16; ++i) {
        int k = s * 16 + i;
        float bk = buf[k];
        float4 w = W4[(size_t)k * 64 + c];
        acc.x = fmaf(bk, w.x, acc.x);
        acc.y = fmaf(bk, w.y, acc.y);
        acc.z = fmaf(bk, w.z, acc.z);
        acc.w = fmaf(bk, w.w, acc.w);
    }
    return acc;
}

// ---- single fused kernel: 1 block (1024 thr) per batch = two 512-thr half-pipelines
// + in-block rho. 16 waves/CU (4/SIMD) so one half's compute covers the other's
// barrier drains. NO cross-block communication (fence poison, R2/R4: +140us).
// __launch_bounds__(1024) SINGLE-ARG: backend caps VGPR at 128 for launchability;
// the 2nd arg is what forced the 64-cap + spill in R5 ((1024,1)->64, (512,4)->64).
__launch_bounds__(1024)
__global__ void deepset(const float* __restrict__ x, const int* __restrict__ mask,
                        const float* __restrict__ pw1, const float* __restrict__ pb1,
                        const float* __restrict__ pw2, const float* __restrict__ pb2,
                        const float* __restrict__ pw3, const float* __restrict__ pb3,
                        const float* __restrict__ rw1, const float* __restrict__ rb1,
                        const float* __restrict__ rw2, const float* __restrict__ rb2,
                        const float* __restrict__ rw3, const float* __restrict__ rb3,
                        float* __restrict__ out)
{
    __shared__ unsigned short xs[2][2][MT * 64];  // [half][dbuf] 32 KB, XOR-swizzled
    __shared__ unsigned short h1s[2][MT * 256];   // 64 KB, XOR-swizzled
    __shared__ short vlist[2][NH2];               // 2 KB
    __shared__ float poolH[2][HID];               // 2 KB
    __shared__ float part[16][HID];               // 16 KB (reused as [32][128] at the end)
    __shared__ float bufB[HID], bufC[HID];        // 2 KB
    __shared__ int cnt_sh[2];

    const int b = blockIdx.x;
    const int t = threadIdx.x;
    const int hh = t >> 9, u = t & 511;           // half id, thread-in-half
    const int lane = u & 63, wq = u >> 6;         // wave lane, wave-in-half (0..7)
    const int quad = lane >> 4, l15 = lane & 15;

    // ---- compact valid indices per half via ballot scan (order irrelevant: sum-pool) ----
    if (t < 2) cnt_sh[t] = 0;
    __syncthreads();
    {
        int m = mask[b * NN + hh * NH2 + u] != 0;
        unsigned long long bal = __ballot(m);     // wave lies entirely within one half
        int pos = __popcll(bal & ((1ULL << lane) - 1ULL));
        int wbase = 0;
        if (lane == 0) wbase = atomicAdd(&cnt_sh[hh], (int)__popcll(bal));
        wbase = __shfl(wbase, 0, 64);
        if (m) vlist[hh][wbase + pos] = (short)u;
    }

    // ---- pack W fragments from GLOBAL fp32 (replaces prep dispatch; L2/L3-resident) ----
    // frag (kk,j): lane holds W[kk*32 + quad*8 + jj][wq*32 + j*16 + l15], jj=0..7
    // (both halves pack identical fragments; duplicate loads are L2 hits)
    uint4 w1f[2][2], w2f[8][2];
    float bias1[2], bias2[2];
#pragma unroll
    for (int j = 0; j < 2; ++j) {
        const int col = wq * 32 + j * 16 + l15;
        bias1[j] = pb1[col]; bias2[j] = pb2[col];
#pragma unroll
        for (int kk = 0; kk < 2; ++kk) {
            unsigned short tmp[8];
#pragma unroll
            for (int jj = 0; jj < 8; ++jj)
                tmp[jj] = f2bf(pw1[(size_t)(kk * 32 + quad * 8 + jj) * HID + col]);
            w1f[kk][j] = *(const uint4*)tmp;
        }
#pragma unroll
        for (int kk = 0; kk < 8; ++kk) {
            unsigned short tmp[8];
#pragma unroll
            for (int jj = 0; jj < 8; ++jj)
                tmp[jj] = f2bf(pw2[(size_t)(kk * 32 + quad * 8 + jj) * HID + col]);
            w2f[kk][j] = *(const uint4*)tmp;
        }
    }

    __syncthreads();
    const int cnt = cnt_sh[hh];                        // own half's count
    const int mx = max(cnt_sh[0], cnt_sh[1]);          // unified trip count (barrier safety)

    float pool[2] = {0.f, 0.f};
    const float* xb = x + ((size_t)b * NN + (size_t)hh * NH2) * DIN;
    const int gr = u >> 3, seg8 = u & 7;                 // gather: row, 16B-block
    const int xoff = gr * 64 + ((seg8 ^ (gr & 7)) << 3); // swizzled xs offset (shorts)

    // ---- preload tile 0 ----
    {
        float4 a0 = make_float4(0.f,0.f,0.f,0.f), a1 = a0;
        if (gr < min(MT, cnt)) {
            const float4* p = (const float4*)(xb + (size_t)vlist[hh][gr] * DIN + seg8 * 8);
            a0 = p[0]; a1 = p[1];
        }
        unsigned short tmp[8] = {f2bf(a0.x),f2bf(a0.y),f2bf(a0.z),f2bf(a0.w),
                                 f2bf(a1.x),f2bf(a1.y),f2bf(a1.z),f2bf(a1.w)};
        *(uint4*)&xs[hh][0][xoff] = *(const uint4*)tmp;
    }

    int cur = 0;
    for (int base = 0; base < mx; base += MT) {
        __syncthreads();                                  // B_top: xs[cur] visible, h1s readers done

        // ---- layer 1: xs -> h1s (K=64) ----
        f32x4 acc[4][2];
#pragma unroll
        for (int f = 0; f < 4; ++f)
#pragma unroll
            for (int j = 0; j < 2; ++j) acc[f][j] = (f32x4){0.f,0.f,0.f,0.f};
#pragma unroll
        for (int kk = 0; kk < 2; ++kk) {
            bf16x8 a[4];
#pragma unroll
            for (int f = 0; f < 4; ++f)
                a[f] = *(const bf16x8*)&xs[hh][cur][(f*16 + l15)*64 + (((kk*4 + quad) ^ (l15 & 7)) << 3)];
#pragma unroll
            for (int j = 0; j < 2; ++j) {
                bf16x8 bw = __builtin_bit_cast(bf16x8, w1f[kk][j]);
#pragma unroll
                for (int f = 0; f < 4; ++f)
                    acc[f][j] = __builtin_amdgcn_mfma_f32_16x16x32_bf16(a[f], bw, acc[f][j], 0, 0, 0);
            }
        }
#pragma unroll
        for (int f = 0; f < 4; ++f)
#pragma unroll
            for (int j = 0; j < 2; ++j) {
                int col = wq * 32 + j * 16 + l15, kb = col >> 3, cl = col & 7;
#pragma unroll
                for (int r = 0; r < 4; ++r) {
                    int row = f * 16 + quad * 4 + r;
                    float h = fmaxf(acc[f][j][r] + bias1[j], 0.f);
                    h1s[hh][row * 256 + ((kb ^ (row & 7)) << 3) + cl] = f2bf(h);
                }
            }

        // ---- prefetch next x tile into regs (drains at B_mid) ----
        float4 n0 = make_float4(0.f,0.f,0.f,0.f), n1 = n0;
        const bool hstore = (base + MT) < mx;             // store decision: unified bound
        if (gr < cnt - (base + MT)) {                     // load guard: own count
            const float4* p = (const float4*)(xb + (size_t)vlist[hh][base + MT + gr] * DIN + seg8 * 8);
            n0 = p[0]; n1 = p[1];
        }
        __syncthreads();                                  // B_mid: h1s visible

        // ---- layer 2: h1s -> pool (K=256), W2 from registers ----
        f32x4 acc2[4][2];
#pragma unroll
        for (int f = 0; f < 4; ++f)
#pragma unroll
            for (int j = 0; j < 2; ++j) acc2[f][j] = (f32x4){0.f,0.f,0.f,0.f};
#pragma unroll
        for (int kk = 0; kk < 8; ++kk) {
            bf16x8 a[4];
#pragma unroll
            for (int f = 0; f < 4; ++f)
                a[f] = *(const bf16x8*)&h1s[hh][(f*16 + l15)*256 + (((kk*4 + quad) ^ (l15 & 7)) << 3)];
#pragma unroll
            for (int j = 0; j < 2; ++j) {
                bf16x8 bw = __builtin_bit_cast(bf16x8, w2f[kk][j]);
#pragma unroll
                for (int f = 0; f < 4; ++f)
                    acc2[f][j] = __builtin_amdgcn_mfma_f32_16x16x32_bf16(a[f], bw, acc2[f][j], 0, 0, 0);
            }
        }
#pragma unroll
        for (int f = 0; f < 4; ++f)
#pragma unroll
            for (int r = 0; r < 4; ++r) {
                bool v = (base + f * 16 + quad * 4 + r) < cnt;
#pragma unroll
                for (int j = 0; j < 2; ++j) {
                    float h = fmaxf(acc2[f][j][r] + bias2[j], 0.f);
                    pool[j] += v ? h : 0.f;
                }
            }

        if (hstore) {
            unsigned short tmp[8] = {f2bf(n0.x),f2bf(n0.y),f2bf(n0.z),f2bf(n0.w),
                                     f2bf(n1.x),f2bf(n1.y),f2bf(n1.z),f2bf(n1.w)};
            *(uint4*)&xs[hh][cur ^ 1][xoff] = *(const uint4*)tmp;
        }
        cur ^= 1;
    }

    // ---- pool reduce per half: cross-quad shuffle, cols wave-disjoint ----
#pragma unroll
    for (int j = 0; j < 2; ++j) {
        float v = pool[j];
        v += __shfl_xor(v, 16, 64);
        v += __shfl_xor(v, 32, 64);
        if (quad == 0) poolH[hh][wq * 32 + j * 16 + l15] = v;
    }
    __syncthreads();

    // ---- combine halves -> pooled vector in bufC ----
    const int ctot = cnt_sh[0] + cnt_sh[1];
    if (t < HID) bufC[t] = poolH[0][t] + poolH[1][t];
    __syncthreads();

    // ---- fused rho (fp32, 1024 threads): folded pw3 + 3-layer chain (R5-verified) ----
    const int c = t & 63, s = t >> 6;                 // 4 cols, 16 k-segs of 16
    {
        float4 p = dotseg16(bufC, pw3, c, s);
        ((float4*)part[s])[c] = p;
        __syncthreads();
        if (t < HID) {
            float v = (float)ctot * pb3[t];
#pragma unroll
            for (int g = 0; g < 16; ++g) v += part[g][t];
            bufB[t] = v;
        }
        __syncthreads();
    }
    {
        float4 p = dotseg16(bufB, rw1, c, s);
        ((float4*)part[s])[c] = p;
        __syncthreads();
        if (t < HID) {
            float v = rb1[t];
#pragma unroll
            for (int g = 0; g < 16; ++g) v += part[g][t];
            bufC[t] = fmaxf(v, 0.f);
        }
        __syncthreads();
    }
    {
        float4 p = dotseg16(bufC, rw2, c, s);
        ((float4*)part[s])[c] = p;
        __syncthreads();
        if (t < HID) {
            float v = rb2[t];
#pragma unroll
            for (int g = 0; g < 16; ++g) v += part[g][t];
            bufB[t] = fmaxf(v, 0.f);
        }
        __syncthreads();
    }
    {   // final layer, N=128: c4=t&31 (4 cols), s4=t>>5 (32 k-segs of 8)
        const int c4 = t & 31, s4 = t >> 5;
        const float4* W4 = (const float4*)rw3;
        float4 acc = make_float4(0.f, 0.f, 0.f, 0.f);
#pragma unroll 8
        for (int i = 0; i < 8; ++i) {
            int k = s4 * 8 + i;
            float bk = bufB[k];
            float4 w = W4[(size_t)k * 32 + c4];
            acc.x = fmaf(bk, w.x, acc.x);
            acc.y = fmaf(bk, w.y, acc.y);
            acc.z = fmaf(bk, w.z, acc.z);
            acc.w = fmaf(bk, w.w, acc.w);
        }
        float* part2 = &part[0][0];               // reuse as [32][128]
        ((float4*)(part2 + s4 * DOUT))[c4] = acc;
        __syncthreads();
        if (t < DOUT) {
            float v = rb3[t];
#pragma unroll
            for (int g = 0; g < 32; ++g) v += part2[g * DOUT + t];
            out[b * DOUT + t] = (ctot > 0) ? v : 0.f;
        }
    }
}
} // namespace

extern "C" void kernel_launch(void* const* d_in, const int* in_sizes, int n_in,
                              void* d_out, int out_size, void* d_ws, size_t ws_size,
                              hipStream_t stream) {
    const float* x    = (const float*)d_in[0];
    const int*   mask = (const int*)  d_in[1];
    const float* pw1  = (const float*)d_in[2];
    const float* pb1  = (const float*)d_in[3];
    const float* pw2  = (const float*)d_in[4];
    const float* pb2  = (const float*)d_in[5];
    const float* pw3  = (const float*)d_in[6];
    const float* pb3  = (const float*)d_in[7];
    const float* rw1  = (const float*)d_in[8];
    const float* rb1  = (const float*)d_in[9];
    const float* rw2  = (const float*)d_in[10];
    const float* rb2  = (const float*)d_in[11];
    const float* rw3  = (const float*)d_in[12];
    const float* rb3  = (const float*)d_in[13];
    float* out = (float*)d_out;
    (void)d_ws; (void)ws_size;   // workspace unused: prep folded in-kernel

    deepset<<<dim3(NB), dim3(1024), 0, stream>>>(x, mask, pw1, pb1, pw2, pb2,
                                                 pw3, pb3, rw1, rb1, rw2, rb2, rw3, rb3, out);
}